// Round 4
// baseline (422.810 us; speedup 1.0000x reference)
//
#include <hip/hip_runtime.h>
#include <cstddef>
#include <cstdint>

#define GAMMA_F 0.99f
#define OMG_F   0.01f      // 1 - gamma
#define EPS_F   1e-5f
#define KN 8192
#define DD 256
#define NN 32768           // B*T

// output layout (float offsets)
#define OFF_ZQ     0
#define OFF_COMMIT 8388608
#define OFF_IDX    8388609
#define OFF_EMB    8421377
#define OFF_MT     10518529
#define OFF_NT     12615681

// segmented-sum chunking
#define C1 32              // positions per level-1 chunk
#define NCH1 (NN / C1)     // 1024 level-1 chunks
#define NREC (NCH1 * 2)    // 2048 level-1 partial records
#define C2 32              // records per level-2 chunk
#define NCH2 (NREC / C2)   // 64 level-2 chunks

typedef _Float16 half8 __attribute__((ext_vector_type(8)));
typedef _Float16 half4 __attribute__((ext_vector_type(4)));
typedef float    f32x4 __attribute__((ext_vector_type(4)));
typedef unsigned long long u64;

// ---------------------------------------------------------------------------
// async 16B global->LDS (DMA: lane i -> lds_base + i*16; base wave-uniform,
// global address must be 16B aligned)
__device__ __forceinline__ void gload16(const void* g, void* l) {
    __builtin_amdgcn_global_load_lds(
        (const __attribute__((address_space(1))) unsigned int*)g,
        (__attribute__((address_space(3))) unsigned int*)l, 16, 0, 0);
}

// sortable pack for exact fp32 rescoring (dist may be negative)
__device__ __forceinline__ u64 packdi(float dist, int n) {
    unsigned u = __float_as_uint(dist);
    u ^= (unsigned)((int)u >> 31) | 0x80000000u;
    return ((u64)u << 32) | (unsigned)n;
}

// ---------------------------------------------------------------------------
// fp32 -> f16 (RNE), vectorized (for ze)
__global__ __launch_bounds__(256) void conv_hi_kernel(
    const float* __restrict__ x, _Float16* __restrict__ hi) {
    const size_t i0 = ((size_t)blockIdx.x * 256 + threadIdx.x) * 4;
    const float4 v = *(const float4*)(x + i0);
    half4 h;
    h[0] = (_Float16)v.x; h[1] = (_Float16)v.y;
    h[2] = (_Float16)v.z; h[3] = (_Float16)v.w;
    *(half4*)(hi + i0) = h;
}

// ---------------------------------------------------------------------------
// fused: W row -> f16 copy + ||w||^2. One wave per code row.
__global__ __launch_bounds__(64) void convw_wsq_kernel(
    const float* __restrict__ W, _Float16* __restrict__ wh,
    float* __restrict__ wsq) {
    const int k = blockIdx.x;
    const int lane = threadIdx.x;
    const float4 v = *(const float4*)(W + (size_t)k * DD + lane * 4);
    half4 h;
    h[0] = (_Float16)v.x; h[1] = (_Float16)v.y;
    h[2] = (_Float16)v.z; h[3] = (_Float16)v.w;
    *(half4*)(wh + (size_t)k * DD + lane * 4) = h;
    float s = v.x * v.x + v.y * v.y + v.z * v.z + v.w * v.w;
#pragma unroll
    for (int off = 32; off > 0; off >>= 1) s += __shfl_down(s, off, 64);
    if (lane == 0) wsq[k] = s;
}

// ---------------------------------------------------------------------------
// Screening GEMM, f16, K=256. Block = 256 points x 256 codes, 8 waves
// (2 point-halves x 4 code-quarters). DEPTH-3 COUNTED-vmcnt PIPELINE:
// BK=32, 4 LDS buffers; per chunk c: issue stage(c+3) (4 gload_lds),
// 12 ds_read_b128, 32 MFMA (setprio-wrapped), s_waitcnt vmcnt(8) (never 0
// mid-loop), raw s_barrier. Writer of buf[x] runs 3 chunks after its last
// reader; reads retire (lgkmcnt before MFMA) before each barrier -> safe.
// LDS swizzle for 64B rows: slot = kgroup ^ (row&3) ^ ((row>>2)&3) ->
// each ds_read_b128's 64 lanes hit 64 distinct 16B cells, bank-balanced;
// DMA writes stay linear (pre-swizzled global source).
// Top-2 selection identical to the validated kernel (tile = 128 codes).
__global__ __launch_bounds__(512, 2) void screen_kernel(
    const _Float16* __restrict__ zh, const _Float16* __restrict__ wh,
    const float* __restrict__ wsq, u64* __restrict__ tmin2) {
    __shared__ __align__(16) _Float16 As[4][256 * 32];   // points, 4x16 KB
    __shared__ __align__(16) _Float16 Bs[4][256 * 32];   // codes,  4x16 KB
    __shared__ __align__(16) u64 top2[256][4];           // [point][code-qtr]

    const int tid  = threadIdx.x;
    const int wave = tid >> 6;          // 0..7
    const int lane = tid & 63;
    const int quad = lane >> 4;
    const int col  = lane & 15;
    const int ph = wave >> 2;           // point half: rows ph*128..+128
    const int cq = wave & 3;            // code quarter: rows cq*64..+64

    // bijective XCD swizzle (4096 blocks % 8 == 0): XCD x sweeps all bn for
    // 16 consecutive bm -> wh (4.2 MB) resident in that XCD's L2.
    const int vid = ((blockIdx.x & 7) << 9) | (blockIdx.x >> 3);
    const int bm = vid >> 5;            // 128 point-blocks
    const int bn = vid & 31;            // 32 code-blocks
    const int m0 = bm * 256;
    const int n0 = bn * 256;

    f32x4 acc[4][8];                    // [ci (codes)][pj (points)]
#pragma unroll
    for (int i = 0; i < 4; i++)
#pragma unroll
        for (int j = 0; j < 8; j++) acc[i][j] = (f32x4){0.f, 0.f, 0.f, 0.f};

    // stage chunk c (K cols c*32..+32) into buffer c&3: 4 DMA issues/wave.
    // lane i of region r=(wave*2+t) writes LDS bytes [r*1024 + i*16, +16)
    // = (row = r*16 + (i>>2), slot = i&3); source k-group g = slot^swz(row).
    auto stage = [&](int c) {
        const int b = c & 3;
        const int d0 = c * 32;
#pragma unroll
        for (int t = 0; t < 2; ++t) {
            const int r = wave * 2 + t;
            const int row = r * 16 + (lane >> 2);
            const int g = (lane & 3) ^ ((row & 3) ^ ((row >> 2) & 3));
            gload16(zh + (size_t)(m0 + row) * DD + d0 + g * 8,
                    &As[b][r * 512]);
            gload16(wh + (size_t)(n0 + row) * DD + d0 + g * 8,
                    &Bs[b][r * 512]);
        }
    };

    // prologue: 3 chunks in flight, wait for chunk 0 (keep 8 outstanding)
    stage(0); stage(1); stage(2);
    asm volatile("s_waitcnt vmcnt(8)" ::: "memory");
    __builtin_amdgcn_s_barrier();
    __builtin_amdgcn_sched_barrier(0);

#define DO_CHUNK(C, DO_STAGE, VMWAIT, DO_SYNC)                               \
    {                                                                         \
        if (DO_STAGE) stage((C) + 3);                                         \
        const _Float16* Ab = As[(C) & 3];                                     \
        const _Float16* Bb = Bs[(C) & 3];                                     \
        half8 a[4], b[8];                                                     \
        _Pragma("unroll")                                                     \
        for (int t = 0; t < 4; ++t) {                                         \
            const int cr = cq * 64 + t * 16 + col;                            \
            const int sl = quad ^ ((cr & 3) ^ ((cr >> 2) & 3));               \
            a[t] = *(const half8*)(Bb + cr * 32 + sl * 8);                    \
        }                                                                     \
        _Pragma("unroll")                                                     \
        for (int t = 0; t < 8; ++t) {                                         \
            const int pr = ph * 128 + t * 16 + col;                           \
            const int sl = quad ^ ((pr & 3) ^ ((pr >> 2) & 3));               \
            b[t] = *(const half8*)(Ab + pr * 32 + sl * 8);                    \
        }                                                                     \
        __builtin_amdgcn_s_setprio(1);                                        \
        _Pragma("unroll")                                                     \
        for (int ci = 0; ci < 4; ++ci)                                        \
            _Pragma("unroll")                                                 \
            for (int pj = 0; pj < 8; ++pj)                                    \
                acc[ci][pj] = __builtin_amdgcn_mfma_f32_16x16x32_f16(         \
                    a[ci], b[pj], acc[ci][pj], 0, 0, 0);                      \
        __builtin_amdgcn_s_setprio(0);                                        \
        if (DO_SYNC) {                                                        \
            asm volatile("s_waitcnt vmcnt(" VMWAIT ")" ::: "memory");         \
            __builtin_amdgcn_s_barrier();                                     \
            __builtin_amdgcn_sched_barrier(0);                                \
        }                                                                     \
    }

    DO_CHUNK(0, true,  "8", true)
    DO_CHUNK(1, true,  "8", true)
    DO_CHUNK(2, true,  "8", true)
    DO_CHUNK(3, true,  "8", true)
    DO_CHUNK(4, true,  "8", true)
    DO_CHUNK(5, false, "4", true)
    DO_CHUNK(6, false, "0", true)
    DO_CHUNK(7, false, "0", false)
#undef DO_CHUNK

    // wq[ci][v] = wsq[code] + 4096 (offset makes all dists positive -> raw
    // f32 bits monotone as u32)
    float wq[4][4];
#pragma unroll
    for (int ci = 0; ci < 4; ++ci) {
        const float4 t =
            *(const float4*)(wsq + n0 + cq * 64 + ci * 16 + quad * 4);
        wq[ci][0] = t.x + 4096.f; wq[ci][1] = t.y + 4096.f;
        wq[ci][2] = t.z + 4096.f; wq[ci][3] = t.w + 4096.f;
    }
    // local code id within this wave's 128-code tile (tile-half = cq&1)
    const unsigned base7 = (unsigned)((cq & 1) * 64 + quad * 4);

#pragma unroll
    for (int pj = 0; pj < 8; ++pj) {
        unsigned t0 = 0xFFFFFFFFu, t1 = 0xFFFFFFFFu;
#pragma unroll
        for (int ci = 0; ci < 4; ++ci)
#pragma unroll
            for (int v = 0; v < 4; ++v) {
                const float dist = fmaf(-2.0f, acc[ci][pj][v], wq[ci][v]);
                const unsigned x = (__float_as_uint(dist) & ~127u) |
                                   (base7 + ci * 16 + v);
                const unsigned mx = t0 > x ? t0 : x;
                t0 = t0 < x ? t0 : x;
                t1 = t1 < mx ? t1 : mx;
            }
        // merge sorted pairs across the 4 quads (same point col)
#pragma unroll
        for (int mk = 16; mk < 64; mk <<= 1) {
            const unsigned o0 = __shfl_xor(t0, mk, 64);
            const unsigned o1 = __shfl_xor(t1, mk, 64);
            const unsigned lo = t0 < o0 ? t0 : o0;
            const unsigned hi = t0 < o0 ? o0 : t0;
            const unsigned mn = t1 < o1 ? t1 : o1;
            t0 = lo;
            t1 = hi < mn ? hi : mn;
        }
        if (quad == 0)
            top2[ph * 128 + pj * 16 + col][cq] = ((u64)t1 << 32) | t0;
    }
    __syncthreads();
    {
        // 512 threads: point p (contiguous per half for coalescing), half h
        const int p = tid & 255;
        const int h = tid >> 8;
        const u64 e0 = top2[p][2 * h], e1 = top2[p][2 * h + 1];
        const unsigned a0 = (unsigned)e0, a1 = (unsigned)(e0 >> 32);
        const unsigned b0 = (unsigned)e1, b1 = (unsigned)(e1 >> 32);
        const unsigned t0 = a0 < b0 ? a0 : b0;
        const unsigned hi = a0 < b0 ? b0 : a0;
        const unsigned mn = a1 < b1 ? a1 : b1;
        const unsigned t1 = hi < mn ? hi : mn;
        const unsigned c1 = n0 + h * 128 + (t0 & 127u);
        const unsigned c2 = n0 + h * 128 + (t1 & 127u);
        const u64 ent = (u64)(t0 & ~127u) | ((u64)c1 << 32) | ((u64)c2 << 48);
        // transposed layout [tile][point] -> coalesced 2KB block write
        tmin2[(size_t)(bn * 2 + h) * NN + m0 + p] = ent;
    }
}

// ---------------------------------------------------------------------------
// Per point (one wave): min over 64 tile records; write window candidates to
// the point's private slots. Fused: zero histogram + pre-init mt_out=g*mt_in
// (needed by the level-2 atomic path of the segmented mt sum).
__global__ __launch_bounds__(256) void compact_kernel(
    const u64* __restrict__ tmin2,
    unsigned* __restrict__ cnt, unsigned* __restrict__ slots,
    unsigned* __restrict__ hist_zero,
    const float* __restrict__ mt_in, float* __restrict__ mt_out) {
    const int tid = threadIdx.x;
    const int gid = blockIdx.x * 256 + tid;
    if (gid < KN) hist_zero[gid] = 0u;
    if (gid < KN * DD / 4) {
        const float4 m = *(const float4*)(mt_in + (size_t)gid * 4);
        float4 r;
        r.x = GAMMA_F * m.x; r.y = GAMMA_F * m.y;
        r.z = GAMMA_F * m.z; r.w = GAMMA_F * m.w;
        *(float4*)(mt_out + (size_t)gid * 4) = r;
    }

    const int lane = tid & 63;
    const int n = blockIdx.x * 4 + (tid >> 6);
    const u64 e = tmin2[(size_t)lane * NN + n];
    const float d1 = __uint_as_float((unsigned)e);   // offset by +4096, quantized
    float mn = d1;
#pragma unroll
    for (int off = 32; off > 0; off >>= 1)
        mn = fminf(mn, __shfl_xor(mn, off, 64));
    const bool q = d1 <= mn + 1.0f;      // >=25-sigma window incl. quantization
    const u64 bal = __ballot(q);
    if (q) {
        const int rank = __popcll(bal & ((1ull << lane) - 1ull));
        if (rank < 16) {
            slots[(size_t)n * 32 + 2 * rank + 0] = (unsigned)(e >> 32) & 0xffffu;
            slots[(size_t)n * 32 + 2 * rank + 1] = (unsigned)(e >> 48);
        }
    }
    if (lane == 0) {
        unsigned c = 2u * (unsigned)__popcll(bal);
        cnt[n] = c < 32u ? c : 32u;
    }
}

// ---------------------------------------------------------------------------
// Fused: exact fp32 rescore of candidates -> winning index; gather zq, write
// zq_st, per-block commit partial, u32 histogram bump. One wave per point.
__global__ __launch_bounds__(256) void rescore_gather_kernel(
    const float* __restrict__ ze, const float* __restrict__ W,
    const unsigned* __restrict__ cnt, const unsigned* __restrict__ slots,
    float* __restrict__ idxf, float* __restrict__ zq_out,
    unsigned* __restrict__ hist, float* __restrict__ partials) {
    const int tid = threadIdx.x;
    const int lane = tid & 63;
    const int n = blockIdx.x * 4 + (tid >> 6);
    const float4 z = *(const float4*)(ze + (size_t)n * DD + lane * 4);
    const unsigned m = cnt[n];
    u64 best = ~0ull;
    for (unsigned j = 0; j < m; ++j) {
        const unsigned c = slots[(size_t)n * 32 + j];
        const float4 w = *(const float4*)(W + (size_t)c * DD + lane * 4);
        float dot = z.x * w.x + z.y * w.y + z.z * w.z + z.w * w.w;
        float wq  = w.x * w.x + w.y * w.y + w.z * w.z + w.w * w.w;
#pragma unroll
        for (int off = 32; off > 0; off >>= 1) {
            dot += __shfl_xor(dot, off, 64);
            wq  += __shfl_xor(wq, off, 64);
        }
        const float dist = fmaf(-2.0f, dot, wq);
        const u64 pk = packdi(dist, (int)c);
        best = best < pk ? best : pk;
    }
    const int idx = (int)(unsigned)(best & 0xFFFFFFFFull);  // wave-uniform
    if (lane == 0) {
        idxf[n] = (float)idx;
        atomicAdd(hist + idx, 1u);          // u32, scattered over 8192 bins
    }

    const float4 w = *(const float4*)(W + (size_t)idx * DD + lane * 4);
    float4 d, o;
    d.x = w.x - z.x; d.y = w.y - z.y; d.z = w.z - z.z; d.w = w.w - z.w;
    o.x = z.x + d.x; o.y = z.y + d.y; o.z = z.z + d.z; o.w = z.w + d.w;
    *(float4*)(zq_out + (size_t)n * DD + lane * 4) = o;

    float c = d.x * d.x + d.y * d.y + d.z * d.z + d.w * d.w;
#pragma unroll
    for (int off = 32; off > 0; off >>= 1) c += __shfl_down(c, off, 64);

    __shared__ float wsum[4];
    if (lane == 0) wsum[tid >> 6] = c;
    __syncthreads();
    if (tid == 0)
        partials[blockIdx.x] = wsum[0] + wsum[1] + wsum[2] + wsum[3];
}

// ---------------------------------------------------------------------------
// Single block: exclusive prefix over the 8192-bin histogram -> bucket start
// offsets; nt_new = gamma*Nt + 0.01*hist; commit = sum(partials)/(N*D).
__global__ __launch_bounds__(256) void prefix_kernel(
    const float* __restrict__ Nt_in, float* __restrict__ ntn,
    const float* __restrict__ partials, float* __restrict__ commit_out,
    unsigned* __restrict__ offsets) {
    const int t = threadIdx.x;
    unsigned* hist = (unsigned*)ntn;
    const int base = t * 32;
    unsigned loc[32];
    unsigned sum = 0;
#pragma unroll
    for (int i = 0; i < 32; ++i) { loc[i] = hist[base + i]; sum += loc[i]; }

    __shared__ unsigned ssum[256];
    __shared__ float cred[256];
    ssum[t] = sum;
    float cp = 0.f;
    for (int i = t; i < NN / 4; i += 256) cp += partials[i];
    cred[t] = cp;
    __syncthreads();

    // Hillis-Steele inclusive scan over 256 per-thread totals
    for (int off = 1; off < 256; off <<= 1) {
        const unsigned v = (t >= off) ? ssum[t - off] : 0u;
        __syncthreads();
        ssum[t] += v;
        __syncthreads();
    }
    unsigned run = (t > 0) ? ssum[t - 1] : 0u;   // exclusive base

    // commit tree reduce
    for (int off = 128; off > 0; off >>= 1) {
        if (t < off) cred[t] += cred[t + off];
        __syncthreads();
    }
    if (t == 0) *commit_out = cred[0] * (1.0f / 8388608.0f);

#pragma unroll
    for (int i = 0; i < 32; ++i) {
        offsets[base + i] = run;
        run += loc[i];
    }
#pragma unroll
    for (int i = 0; i < 32; ++i)
        ntn[base + i] = GAMMA_F * Nt_in[base + i] + OMG_F * (float)loc[i];
}

// ---------------------------------------------------------------------------
// Counting-sort scatter: perm[pos] = point, codes[pos] = its code.
__global__ __launch_bounds__(256) void scatter_kernel(
    const float* __restrict__ idxf, unsigned* __restrict__ offsets,
    unsigned* __restrict__ perm, unsigned* __restrict__ codes) {
    const int n = blockIdx.x * 256 + threadIdx.x;
    const int idx = (int)idxf[n];
    const unsigned pos = atomicAdd(offsets + idx, 1u);
    perm[pos] = n;
    codes[pos] = (unsigned)idx;
}

// ---------------------------------------------------------------------------
// Segmented sum, level 1: 1024 waves x 32-position chunks over the sorted
// (codes, perm) sequence. Interior runs (exclusive ownership) are written
// directly: mt_new = g*mt + 0.01*sum. Each chunk's first and last run are
// ALWAYS emitted as 2 partial records (code-sorted order preserved; a
// single-run chunk emits (c,sum),(c,0)). Worst-case work per wave = 32 rows,
// independent of bucket skew.
__global__ __launch_bounds__(256) void mt1_kernel(
    const float* __restrict__ ze, const float* __restrict__ mt_in,
    const unsigned* __restrict__ perm, const unsigned* __restrict__ codes,
    float* __restrict__ mt_out, unsigned* __restrict__ prec,
    float* __restrict__ pdata) {
    const int tid = threadIdx.x;
    const int lane = tid & 63;
    const int w = blockIdx.x * 4 + (tid >> 6);   // chunk id, 0..NCH1-1
    const int j0 = w * C1;

    unsigned ccur = codes[j0];
    bool first = true;
    float4 acc = {0.f, 0.f, 0.f, 0.f};

    for (int j = j0; j < j0 + C1; ++j) {
        const unsigned c = codes[j];
        if (c != ccur) {
            if (first) {
                *(float4*)(pdata + (size_t)(2 * w) * DD + lane * 4) = acc;
                if (lane == 0) prec[2 * w] = ccur;
                first = false;
            } else {
                const size_t o = (size_t)ccur * DD + lane * 4;
                const float4 m = *(const float4*)(mt_in + o);
                float4 r;
                r.x = GAMMA_F * m.x + OMG_F * acc.x;
                r.y = GAMMA_F * m.y + OMG_F * acc.y;
                r.z = GAMMA_F * m.z + OMG_F * acc.z;
                r.w = GAMMA_F * m.w + OMG_F * acc.w;
                *(float4*)(mt_out + o) = r;
            }
            acc = (float4){0.f, 0.f, 0.f, 0.f};
            ccur = c;
        }
        const unsigned p = perm[j];
        const float4 z = *(const float4*)(ze + (size_t)p * DD + lane * 4);
        acc.x += z.x; acc.y += z.y; acc.z += z.z; acc.w += z.w;
    }
    // tail: last run always emitted
    if (first) {   // whole chunk was one run -> record + zero dummy (same code)
        *(float4*)(pdata + (size_t)(2 * w) * DD + lane * 4) = acc;
        *(float4*)(pdata + (size_t)(2 * w + 1) * DD + lane * 4) =
            (float4){0.f, 0.f, 0.f, 0.f};
        if (lane == 0) { prec[2 * w] = ccur; prec[2 * w + 1] = ccur; }
    } else {
        *(float4*)(pdata + (size_t)(2 * w + 1) * DD + lane * 4) = acc;
        if (lane == 0) prec[2 * w + 1] = ccur;
    }
}

// ---------------------------------------------------------------------------
// Segmented sum, level 2: 64 waves x 32-record chunks over the 2048 records
// (still code-sorted). Interior runs -> direct write. First/last runs ->
// atomicAdd(0.01*partial) onto mt_out (pre-inited to g*mt in compact_kernel).
// Worst case ~2 atomic flushes per chunk -> <=32K scattered fp32 atomics.
__global__ __launch_bounds__(256) void mt2_kernel(
    const float* __restrict__ mt_in, const unsigned* __restrict__ prec,
    const float* __restrict__ pdata, float* __restrict__ mt_out) {
    const int tid = threadIdx.x;
    const int lane = tid & 63;
    const int w = blockIdx.x * 4 + (tid >> 6);   // 0..NCH2-1
    const int r0 = w * C2;

    unsigned ccur = prec[r0];
    bool first = true;
    float4 acc = {0.f, 0.f, 0.f, 0.f};

    for (int r = r0; r < r0 + C2; ++r) {
        const unsigned c = prec[r];
        if (c != ccur) {
            if (first) {
                float* mp = mt_out + (size_t)ccur * DD + lane * 4;
                atomicAdd(mp + 0, OMG_F * acc.x);
                atomicAdd(mp + 1, OMG_F * acc.y);
                atomicAdd(mp + 2, OMG_F * acc.z);
                atomicAdd(mp + 3, OMG_F * acc.w);
                first = false;
            } else {
                const size_t o = (size_t)ccur * DD + lane * 4;
                const float4 m = *(const float4*)(mt_in + o);
                float4 rr;
                rr.x = GAMMA_F * m.x + OMG_F * acc.x;
                rr.y = GAMMA_F * m.y + OMG_F * acc.y;
                rr.z = GAMMA_F * m.z + OMG_F * acc.z;
                rr.w = GAMMA_F * m.w + OMG_F * acc.w;
                *(float4*)(mt_out + o) = rr;
            }
            acc = (float4){0.f, 0.f, 0.f, 0.f};
            ccur = c;
        }
        const float4 v = *(const float4*)(pdata + (size_t)r * DD + lane * 4);
        acc.x += v.x; acc.y += v.y; acc.z += v.z; acc.w += v.w;
    }
    // last run: always atomic (may continue into the next chunk)
    float* mp = mt_out + (size_t)ccur * DD + lane * 4;
    atomicAdd(mp + 0, OMG_F * acc.x);
    atomicAdd(mp + 1, OMG_F * acc.y);
    atomicAdd(mp + 2, OMG_F * acc.z);
    atomicAdd(mp + 3, OMG_F * acc.w);
}

// ---------------------------------------------------------------------------
// emb = mt_new / Nn (mt blend already done in mt1/mt2)
__global__ __launch_bounds__(256) void final_kernel(
    const float* __restrict__ nt_new, const float* __restrict__ mt_new,
    float* __restrict__ emb_out) {
    __shared__ float red[256];
    float s = 0.0f;
    for (int i = threadIdx.x; i < KN; i += 256) s += nt_new[i];
    red[threadIdx.x] = s;
    __syncthreads();
    for (int off = 128; off > 0; off >>= 1) {
        if (threadIdx.x < off) red[threadIdx.x] += red[threadIdx.x + off];
        __syncthreads();
    }
    const float n = red[0];

    const size_t i0 = ((size_t)blockIdx.x * 256 + threadIdx.x) * 4;
    const int k = (int)(i0 >> 8);

    const float4 mt = *(const float4*)(mt_new + i0);
    const float Nn = (nt_new[k] + EPS_F) * n / (n + (float)KN * EPS_F);
    float4 e;
    e.x = mt.x / Nn;
    e.y = mt.y / Nn;
    e.z = mt.z / Nn;
    e.w = mt.w / Nn;
    *(float4*)(emb_out + i0) = e;
}

// ---------------------------------------------------------------------------
extern "C" void kernel_launch(void* const* d_in, const int* in_sizes, int n_in,
                              void* d_out, int out_size, void* d_ws, size_t ws_size,
                              hipStream_t stream) {
    const float* ze = (const float*)d_in[0];
    const float* W  = (const float*)d_in[1];
    const float* mt = (const float*)d_in[2];
    const float* Nt = (const float*)d_in[3];

    float* out    = (float*)d_out;
    float* zq_out = out + OFF_ZQ;
    float* commit = out + OFF_COMMIT;
    float* idxf   = out + OFF_IDX;
    float* emb    = out + OFF_EMB;
    float* mtn    = out + OFF_MT;
    float* ntn    = out + OFF_NT;

    // ---- scratch aliases (aligned; all consumed before real outputs written)
    _Float16* zh = (_Float16*)zq_out;                  // NN*DD halfs (16.7 MB)
    u64* tmin2 =                                       // [64 tiles][NN points]
        (u64*)(zq_out + (size_t)NN * DD / 2);
    _Float16* wh = (_Float16*)(mtn + 3);               // 16B-aligned
    float* wsqbuf = idxf + 3;                          // 16B-aligned scratch in
                                                       // idx region (KN floats)
    // emb region (KN*DD floats = 2,097,152 u32) scratch layout:
    unsigned* cnt      = (unsigned*)emb;                       // NN
    unsigned* slots    = cnt + NN;                             // NN*32
    float*    partials = (float*)(slots + (size_t)NN * 32);    // NN/4
    unsigned* offsets  = (unsigned*)partials + NN / 4;         // KN
    unsigned* perm     = offsets + KN;                         // NN
    unsigned* codes    = perm + NN;                            // NN
    unsigned* prec     = codes + NN;                           // NREC
    float*    pdata    = (float*)(prec + NREC);                // NREC*DD (2MB)
    unsigned* hist     = (unsigned*)ntn;               // KN u32 (aliased nt)

    // 1) f16 conversions (+ fused ||w||^2 for W)
    conv_hi_kernel<<<(NN * DD / 4) / 256, 256, 0, stream>>>(ze, zh);
    convw_wsq_kernel<<<KN, 64, 0, stream>>>(W, wh, wsqbuf);

    // 2) f16 screening GEMM (256x256 tiles, 8 waves, depth-3 counted-vmcnt)
    screen_kernel<<<(NN / 256) * (KN / 256), 512, 0, stream>>>(
        zh, wh, wsqbuf, tmin2);

    // 3) window compaction; fused: zero hist + pre-init mt_out = g*mt_in
    compact_kernel<<<NN / 4, 256, 0, stream>>>(tmin2, cnt, slots, hist,
                                               mt, mtn);

    // 4) exact fp32 rescore + gather + zq write + histogram + commit partials
    rescore_gather_kernel<<<NN / 4, 256, 0, stream>>>(
        ze, W, cnt, slots, idxf, zq_out, hist, partials);

    // 5) prefix sum over histogram -> bucket offsets; nt_new; commit
    prefix_kernel<<<1, 256, 0, stream>>>(Nt, ntn, partials, commit, offsets);

    // 6) counting-sort scatter -> perm + codes
    scatter_kernel<<<NN / 256, 256, 0, stream>>>(idxf, offsets, perm, codes);

    // 7) segmented sum level 1: balanced chunks, direct interior writes,
    //    2 partial records per chunk
    mt1_kernel<<<NCH1 / 4, 256, 0, stream>>>(ze, mt, perm, codes, mtn,
                                             prec, pdata);

    // 8) segmented sum level 2: reduce 2048 records, atomic only at chunk
    //    boundaries
    mt2_kernel<<<NCH2 / 4, 256, 0, stream>>>(mt, prec, pdata, mtn);

    // 9) emb = mt_new / Nn (overwrites scratch in emb region)
    final_kernel<<<(KN * DD / 4) / 256, 256, 0, stream>>>(ntn, mtn, emb);
}

// Round 6
// 362.736 us; speedup vs baseline: 1.1656x; 1.1656x over previous
//
#include <hip/hip_runtime.h>
#include <cstddef>
#include <cstdint>

#define GAMMA_F 0.99f
#define OMG_F   0.01f      // 1 - gamma
#define EPS_F   1e-5f
#define KN 8192
#define DD 256
#define NN 32768           // B*T

// output layout (float offsets)
#define OFF_ZQ     0
#define OFF_COMMIT 8388608
#define OFF_IDX    8388609
#define OFF_EMB    8421377
#define OFF_MT     10518529
#define OFF_NT     12615681

// segmented-sum chunking
#define C1 32              // positions per level-1 chunk
#define NCH1 (NN / C1)     // 1024 level-1 chunks
#define NREC (NCH1 * 2)    // 2048 level-1 partial records
#define C2 32              // records per level-2 chunk
#define NCH2 (NREC / C2)   // 64 level-2 chunks

typedef _Float16 half8 __attribute__((ext_vector_type(8)));
typedef _Float16 half4 __attribute__((ext_vector_type(4)));
typedef float    f32x4 __attribute__((ext_vector_type(4)));
typedef unsigned long long u64;

// ---------------------------------------------------------------------------
// async 16B global->LDS (DMA: lane i -> lds_base + i*16; base wave-uniform,
// global address must be 16B aligned)
__device__ __forceinline__ void gload16(const void* g, void* l) {
    __builtin_amdgcn_global_load_lds(
        (const __attribute__((address_space(1))) unsigned int*)g,
        (__attribute__((address_space(3))) unsigned int*)l, 16, 0, 0);
}

// sortable pack for exact fp32 rescoring (dist may be negative)
__device__ __forceinline__ u64 packdi(float dist, int n) {
    unsigned u = __float_as_uint(dist);
    u ^= (unsigned)((int)u >> 31) | 0x80000000u;
    return ((u64)u << 32) | (unsigned)n;
}

// ---------------------------------------------------------------------------
// Fused prep: ze -> f16 (all 8192 blocks); W row -> f16 + ||w||^2 (blocks
// 0..2047, one wave per code row); zero the index histogram.
__global__ __launch_bounds__(256) void prep_kernel(
    const float* __restrict__ ze, const float* __restrict__ W,
    _Float16* __restrict__ zh, _Float16* __restrict__ wh,
    float* __restrict__ wsq, unsigned* __restrict__ hist_zero) {
    const int tid = threadIdx.x;
    const size_t gid = (size_t)blockIdx.x * 256 + tid;

    {   // ze conversion, 4 floats per thread
        const size_t i0 = gid * 4;
        const float4 v = *(const float4*)(ze + i0);
        half4 h;
        h[0] = (_Float16)v.x; h[1] = (_Float16)v.y;
        h[2] = (_Float16)v.z; h[3] = (_Float16)v.w;
        *(half4*)(zh + i0) = h;
    }
    if (gid < KN) hist_zero[gid] = 0u;

    if (blockIdx.x < KN / 4) {           // W rows, one wave per row
        const int k = blockIdx.x * 4 + (tid >> 6);
        const int lane = tid & 63;
        const float4 v = *(const float4*)(W + (size_t)k * DD + lane * 4);
        half4 h;
        h[0] = (_Float16)v.x; h[1] = (_Float16)v.y;
        h[2] = (_Float16)v.z; h[3] = (_Float16)v.w;
        *(half4*)(wh + (size_t)k * DD + lane * 4) = h;
        float s = v.x * v.x + v.y * v.y + v.z * v.z + v.w * v.w;
#pragma unroll
        for (int off = 32; off > 0; off >>= 1) s += __shfl_down(s, off, 64);
        if (lane == 0) wsq[k] = s;
    }
}

// ---------------------------------------------------------------------------
// Screening GEMM, f16, K=256. Block = 128 points x 128 codes, 4 waves (2x2).
// (Validated 165us round-2 version; only the tmin2 store is split into
// lo/hi u32 arrays because the new scratch base is not 8B-aligned.)
__global__ __launch_bounds__(256, 4) void screen_kernel(
    const _Float16* __restrict__ zh, const _Float16* __restrict__ wh,
    const float* __restrict__ wsq,
    unsigned* __restrict__ tlo, unsigned* __restrict__ thi) {
    __shared__ __align__(16) _Float16 As[128 * 64];   // points tile, 16 KB
    __shared__ __align__(16) _Float16 Bs[128 * 64];   // codes tile, 16 KB
    __shared__ __align__(16) u64 top2[128][2];        // [point][code-half]

    const int tid  = threadIdx.x;
    const int wave = tid >> 6;
    const int lane = tid & 63;
    const int quad = lane >> 4;
    const int col  = lane & 15;
    const int ph = wave & 1;        // point half of the block tile
    const int ch = wave >> 1;       // code half
    const int pw = ph * 64;
    const int cw = ch * 64;

    const int bm = blockIdx.x >> 6;     // point-block
    const int bn = blockIdx.x & 63;     // code-block
    const int m0 = bm * 128;
    const int n0 = bn * 128;

    f32x4 acc[4][4];                // [ci (codes)][pj (points)]
#pragma unroll
    for (int i = 0; i < 4; i++)
#pragma unroll
        for (int j = 0; j < 4; j++) acc[i][j] = (f32x4){0.f, 0.f, 0.f, 0.f};

    for (int c = 0; c < 4; ++c) {            // K = 256, 4 chunks of 64
        const int d0 = c * 64;
        __syncthreads();
#pragma unroll
        for (int i = 0; i < 4; ++i) {
            const int clin = (wave * 4 + i) * 64 + lane;   // 0..1023
            const int mrow = clin >> 3;
            const int p = clin & 7;
            const int q = p ^ (mrow & 7);                  // swizzled k-chunk
            gload16(zh + (size_t)(m0 + mrow) * DD + d0 + q * 8,
                    As + (wave * 4 + i) * 512);
            gload16(wh + (size_t)(n0 + mrow) * DD + d0 + q * 8,
                    Bs + (wave * 4 + i) * 512);
        }
        __syncthreads();

#pragma unroll
        for (int kk = 0; kk < 2; ++kk) {
            half8 a[4], b[4];
#pragma unroll
            for (int t = 0; t < 4; ++t) {
                const int cr = cw + t * 16 + col;   // code row
                const int pr = pw + t * 16 + col;   // point row
                const int cc = kk * 4 + quad;
                a[t] = *(const half8*)(Bs + cr * 64 + (cc ^ (cr & 7)) * 8);
                b[t] = *(const half8*)(As + pr * 64 + (cc ^ (pr & 7)) * 8);
            }
#pragma unroll
            for (int ci = 0; ci < 4; ++ci)
#pragma unroll
                for (int pj = 0; pj < 4; ++pj)
                    acc[ci][pj] = __builtin_amdgcn_mfma_f32_16x16x32_f16(
                        a[ci], b[pj], acc[ci][pj], 0, 0, 0);
        }
    }

    // wq[ci][v] = wsq[code] + 4096 (offset makes all dists positive -> raw
    // f32 bits monotone as u32)
    float wq[4][4];
#pragma unroll
    for (int ci = 0; ci < 4; ++ci) {
        const float4 t = *(const float4*)(wsq + n0 + cw + ci * 16 + quad * 4);
        wq[ci][0] = t.x + 4096.f; wq[ci][1] = t.y + 4096.f;
        wq[ci][2] = t.z + 4096.f; wq[ci][3] = t.w + 4096.f;
    }
    const unsigned base7 = (unsigned)(cw + quad * 4);

#pragma unroll
    for (int pj = 0; pj < 4; ++pj) {
        unsigned t0 = 0xFFFFFFFFu, t1 = 0xFFFFFFFFu;
#pragma unroll
        for (int ci = 0; ci < 4; ++ci)
#pragma unroll
            for (int v = 0; v < 4; ++v) {
                const float dist = fmaf(-2.0f, acc[ci][pj][v], wq[ci][v]);
                const unsigned x = (__float_as_uint(dist) & ~127u) |
                                   (base7 + ci * 16 + v);
                const unsigned mx = t0 > x ? t0 : x;
                t0 = t0 < x ? t0 : x;
                t1 = t1 < mx ? t1 : mx;
            }
        // merge sorted pairs across the 4 quads (same point col)
#pragma unroll
        for (int mk = 16; mk < 64; mk <<= 1) {
            const unsigned o0 = __shfl_xor(t0, mk, 64);
            const unsigned o1 = __shfl_xor(t1, mk, 64);
            const unsigned lo = t0 < o0 ? t0 : o0;
            const unsigned hi = t0 < o0 ? o0 : t0;
            const unsigned mn = t1 < o1 ? t1 : o1;
            t0 = lo;
            t1 = hi < mn ? hi : mn;
        }
        if (quad == 0)
            top2[pw + pj * 16 + col][ch] = ((u64)t1 << 32) | t0;
    }
    __syncthreads();
    if (tid < 128) {
        const u64 e0 = top2[tid][0], e1 = top2[tid][1];
        const unsigned a0 = (unsigned)e0, a1 = (unsigned)(e0 >> 32);
        const unsigned b0 = (unsigned)e1, b1 = (unsigned)(e1 >> 32);
        const unsigned t0 = a0 < b0 ? a0 : b0;
        const unsigned hi = a0 < b0 ? b0 : a0;
        const unsigned mn = a1 < b1 ? a1 : b1;
        const unsigned t1 = hi < mn ? hi : mn;
        const unsigned c1 = n0 + (t0 & 127u);
        const unsigned c2 = n0 + (t1 & 127u);
        const u64 ent = (u64)(t0 & ~127u) | ((u64)c1 << 32) | ((u64)c2 << 48);
        // transposed layout [tile][point] -> coalesced 512B block writes
        tlo[(size_t)bn * NN + m0 + tid] = (unsigned)ent;
        thi[(size_t)bn * NN + m0 + tid] = (unsigned)(ent >> 32);
    }
}

// ---------------------------------------------------------------------------
// FUSED select = compact + rescore. Per point (one wave): min over 64 tile
// records -> window candidates in LDS (no global round-trip); exact fp32
// rescore -> winning index, zq write, histogram bump. The per-block commit
// partial is written into tlo[4*blockIdx] -- a tmin2 slot this block alone
// consumed (no cross-block hazard; tmin2 lives outside the zq region now).
__global__ __launch_bounds__(256) void select_kernel(
    const unsigned* __restrict__ tlo, const unsigned* __restrict__ thi,
    const float* __restrict__ ze, const float* __restrict__ W,
    float* __restrict__ idxf, float* __restrict__ zq_out,
    unsigned* __restrict__ hist, float* __restrict__ partials) {
    __shared__ unsigned sl[4][32];
    __shared__ float wsum[4];
    const int tid = threadIdx.x;
    const int lane = tid & 63;
    const int w = tid >> 6;

    const int n = blockIdx.x * 4 + w;
    const unsigned elo = tlo[(size_t)lane * NN + n];
    const unsigned ehi = thi[(size_t)lane * NN + n];
    const float d1 = __uint_as_float(elo);   // offset +4096, quantized
    float mn = d1;
#pragma unroll
    for (int off = 32; off > 0; off >>= 1)
        mn = fminf(mn, __shfl_xor(mn, off, 64));
    const bool q = d1 <= mn + 1.0f;      // >=25-sigma window incl. quantization
    const u64 bal = __ballot(q);
    if (q) {
        const int rank = __popcll(bal & ((1ull << lane) - 1ull));
        if (rank < 16) {
            sl[w][2 * rank + 0] = ehi & 0xffffu;
            sl[w][2 * rank + 1] = ehi >> 16;
        }
    }
    unsigned m = 2u * (unsigned)__popcll(bal);
    m = m < 32u ? m : 32u;
    __syncthreads();                     // slots visible

    const float4 z = *(const float4*)(ze + (size_t)n * DD + lane * 4);
    u64 best = ~0ull;
    for (unsigned j = 0; j < m; ++j) {
        const unsigned c = sl[w][j];
        const float4 ww = *(const float4*)(W + (size_t)c * DD + lane * 4);
        float dot = z.x * ww.x + z.y * ww.y + z.z * ww.z + z.w * ww.w;
        float wq  = ww.x * ww.x + ww.y * ww.y + ww.z * ww.z + ww.w * ww.w;
#pragma unroll
        for (int off = 32; off > 0; off >>= 1) {
            dot += __shfl_xor(dot, off, 64);
            wq  += __shfl_xor(wq, off, 64);
        }
        const float dist = fmaf(-2.0f, dot, wq);
        const u64 pk = packdi(dist, (int)c);
        best = best < pk ? best : pk;
    }
    const int idx = (int)(unsigned)(best & 0xFFFFFFFFull);  // wave-uniform
    if (lane == 0) {
        idxf[n] = (float)idx;
        atomicAdd(hist + idx, 1u);          // u32, scattered over 8192 bins
    }

    const float4 ww = *(const float4*)(W + (size_t)idx * DD + lane * 4);
    float4 d, o;
    d.x = ww.x - z.x; d.y = ww.y - z.y; d.z = ww.z - z.z; d.w = ww.w - z.w;
    o.x = z.x + d.x; o.y = z.y + d.y; o.z = z.z + d.z; o.w = z.w + d.w;
    *(float4*)(zq_out + (size_t)n * DD + lane * 4) = o;

    float c = d.x * d.x + d.y * d.y + d.z * d.z + d.w * d.w;
#pragma unroll
    for (int off = 32; off > 0; off >>= 1) c += __shfl_down(c, off, 64);

    if (lane == 0) wsum[w] = c;
    __syncthreads();                     // all tmin2 reads of this block done
    if (tid == 0)
        partials[4 * blockIdx.x] = wsum[0] + wsum[1] + wsum[2] + wsum[3];
}

// ---------------------------------------------------------------------------
// Single block: exclusive prefix over the 8192-bin histogram -> bucket start
// offsets; nt_new = gamma*Nt + 0.01*hist; commit = sum(partials)/(N*D);
// n = sum(nt_new) -> workspace. Reads partials (stride-4 slots in the dead
// tmin2 area) BEFORE writing offsets over the same region (single block,
// ordered by __syncthreads).
__global__ __launch_bounds__(256) void prefix_kernel(
    const float* __restrict__ Nt_in, float* __restrict__ ntn,
    const float* __restrict__ partials, float* __restrict__ commit_out,
    unsigned* __restrict__ offsets, float* __restrict__ nws) {
    const int t = threadIdx.x;
    unsigned* hist = (unsigned*)ntn;
    const int base = t * 32;
    unsigned loc[32];
    unsigned sum = 0;
#pragma unroll
    for (int i = 0; i < 32; ++i) { loc[i] = hist[base + i]; sum += loc[i]; }

    __shared__ unsigned ssum[256];
    __shared__ float cred[256];
    __shared__ float fred[256];
    ssum[t] = sum;
    float cp = 0.f;
    for (int i = t; i < NN / 4; i += 256) cp += partials[4 * i];
    cred[t] = cp;
    __syncthreads();

    // Hillis-Steele inclusive scan over 256 per-thread totals
    for (int off = 1; off < 256; off <<= 1) {
        const unsigned v = (t >= off) ? ssum[t - off] : 0u;
        __syncthreads();
        ssum[t] += v;
        __syncthreads();
    }
    unsigned run = (t > 0) ? ssum[t - 1] : 0u;   // exclusive base

    // commit tree reduce
    for (int off = 128; off > 0; off >>= 1) {
        if (t < off) cred[t] += cred[t + off];
        __syncthreads();
    }
    if (t == 0) *commit_out = cred[0] * (1.0f / 8388608.0f);

#pragma unroll
    for (int i = 0; i < 32; ++i) {
        offsets[base + i] = run;
        run += loc[i];
    }
    float fs = 0.f;
#pragma unroll
    for (int i = 0; i < 32; ++i) {
        const float v = GAMMA_F * Nt_in[base + i] + OMG_F * (float)loc[i];
        ntn[base + i] = v;
        fs += v;
    }
    fred[t] = fs;
    __syncthreads();
    for (int off = 128; off > 0; off >>= 1) {
        if (t < off) fred[t] += fred[t + off];
        __syncthreads();
    }
    if (t == 0) nws[0] = fred[0];
}

// ---------------------------------------------------------------------------
// Counting-sort scatter (blocks 0..127) + fused mt pre-init = g*mt_in over
// the full grid (2048 blocks; tmin2 dead by now, mt region writable).
__global__ __launch_bounds__(256) void scatter_kernel(
    const float* __restrict__ idxf, unsigned* __restrict__ offsets,
    unsigned* __restrict__ perm, unsigned* __restrict__ codes,
    const float* __restrict__ mt_in, float* __restrict__ mt_out) {
    const size_t gid = (size_t)blockIdx.x * 256 + threadIdx.x;
    {   // 2048*256 threads x 4 floats == KN*DD exactly
        const float4 m = *(const float4*)(mt_in + gid * 4);
        float4 r;
        r.x = GAMMA_F * m.x; r.y = GAMMA_F * m.y;
        r.z = GAMMA_F * m.z; r.w = GAMMA_F * m.w;
        *(float4*)(mt_out + gid * 4) = r;
    }
    if (gid < NN) {
        const int idx = (int)idxf[gid];
        const unsigned pos = atomicAdd(offsets + idx, 1u);
        perm[pos] = (unsigned)gid;
        codes[pos] = (unsigned)idx;
    }
}

// ---------------------------------------------------------------------------
// Segmented sum, level 1: 1024 waves x 32-position chunks over the sorted
// (codes, perm) sequence. Interior runs -> direct write mt_new = g*mt+0.01*s.
// First/last runs of each chunk -> 2 partial records (code-sorted order).
// Worst-case work per wave = 32 rows, independent of bucket skew.
__global__ __launch_bounds__(256) void mt1_kernel(
    const float* __restrict__ ze, const float* __restrict__ mt_in,
    const unsigned* __restrict__ perm, const unsigned* __restrict__ codes,
    float* __restrict__ mt_out, unsigned* __restrict__ prec,
    float* __restrict__ pdata) {
    const int tid = threadIdx.x;
    const int lane = tid & 63;
    const int w = blockIdx.x * 4 + (tid >> 6);   // chunk id, 0..NCH1-1
    const int j0 = w * C1;

    unsigned ccur = codes[j0];
    bool first = true;
    float4 acc = {0.f, 0.f, 0.f, 0.f};

    for (int j = j0; j < j0 + C1; ++j) {
        const unsigned c = codes[j];
        if (c != ccur) {
            if (first) {
                *(float4*)(pdata + (size_t)(2 * w) * DD + lane * 4) = acc;
                if (lane == 0) prec[2 * w] = ccur;
                first = false;
            } else {
                const size_t o = (size_t)ccur * DD + lane * 4;
                const float4 m = *(const float4*)(mt_in + o);
                float4 r;
                r.x = GAMMA_F * m.x + OMG_F * acc.x;
                r.y = GAMMA_F * m.y + OMG_F * acc.y;
                r.z = GAMMA_F * m.z + OMG_F * acc.z;
                r.w = GAMMA_F * m.w + OMG_F * acc.w;
                *(float4*)(mt_out + o) = r;
            }
            acc = (float4){0.f, 0.f, 0.f, 0.f};
            ccur = c;
        }
        const unsigned p = perm[j];
        const float4 z = *(const float4*)(ze + (size_t)p * DD + lane * 4);
        acc.x += z.x; acc.y += z.y; acc.z += z.z; acc.w += z.w;
    }
    // tail: last run always emitted
    if (first) {   // whole chunk was one run -> record + zero dummy (same code)
        *(float4*)(pdata + (size_t)(2 * w) * DD + lane * 4) = acc;
        *(float4*)(pdata + (size_t)(2 * w + 1) * DD + lane * 4) =
            (float4){0.f, 0.f, 0.f, 0.f};
        if (lane == 0) { prec[2 * w] = ccur; prec[2 * w + 1] = ccur; }
    } else {
        *(float4*)(pdata + (size_t)(2 * w + 1) * DD + lane * 4) = acc;
        if (lane == 0) prec[2 * w + 1] = ccur;
    }
}

// ---------------------------------------------------------------------------
// Segmented sum, level 2: 64 waves x 32-record chunks over the 2048 records
// (still code-sorted). Interior runs -> direct write. First/last runs ->
// atomicAdd(0.01*partial) onto mt_out (pre-inited to g*mt in scatter_kernel).
__global__ __launch_bounds__(256) void mt2_kernel(
    const float* __restrict__ mt_in, const unsigned* __restrict__ prec,
    const float* __restrict__ pdata, float* __restrict__ mt_out) {
    const int tid = threadIdx.x;
    const int lane = tid & 63;
    const int w = blockIdx.x * 4 + (tid >> 6);   // 0..NCH2-1
    const int r0 = w * C2;

    unsigned ccur = prec[r0];
    bool first = true;
    float4 acc = {0.f, 0.f, 0.f, 0.f};

    for (int r = r0; r < r0 + C2; ++r) {
        const unsigned c = prec[r];
        if (c != ccur) {
            if (first) {
                float* mp = mt_out + (size_t)ccur * DD + lane * 4;
                atomicAdd(mp + 0, OMG_F * acc.x);
                atomicAdd(mp + 1, OMG_F * acc.y);
                atomicAdd(mp + 2, OMG_F * acc.z);
                atomicAdd(mp + 3, OMG_F * acc.w);
                first = false;
            } else {
                const size_t o = (size_t)ccur * DD + lane * 4;
                const float4 m = *(const float4*)(mt_in + o);
                float4 rr;
                rr.x = GAMMA_F * m.x + OMG_F * acc.x;
                rr.y = GAMMA_F * m.y + OMG_F * acc.y;
                rr.z = GAMMA_F * m.z + OMG_F * acc.z;
                rr.w = GAMMA_F * m.w + OMG_F * acc.w;
                *(float4*)(mt_out + o) = rr;
            }
            acc = (float4){0.f, 0.f, 0.f, 0.f};
            ccur = c;
        }
        const float4 v = *(const float4*)(pdata + (size_t)r * DD + lane * 4);
        acc.x += v.x; acc.y += v.y; acc.z += v.z; acc.w += v.w;
    }
    // last run: always atomic (may continue into the next chunk)
    float* mp = mt_out + (size_t)ccur * DD + lane * 4;
    atomicAdd(mp + 0, OMG_F * acc.x);
    atomicAdd(mp + 1, OMG_F * acc.y);
    atomicAdd(mp + 2, OMG_F * acc.z);
    atomicAdd(mp + 3, OMG_F * acc.w);
}

// ---------------------------------------------------------------------------
// emb = mt_new / Nn; n precomputed by prefix (no per-block 8K reduction).
__global__ __launch_bounds__(256) void final_kernel(
    const float* __restrict__ nt_new, const float* __restrict__ mt_new,
    const float* __restrict__ nws, float* __restrict__ emb_out) {
    const float n = nws[0];
    const size_t i0 = ((size_t)blockIdx.x * 256 + threadIdx.x) * 4;
    const int k = (int)(i0 >> 8);

    const float4 mt = *(const float4*)(mt_new + i0);
    const float Nn = (nt_new[k] + EPS_F) * n / (n + (float)KN * EPS_F);
    float4 e;
    e.x = mt.x / Nn;
    e.y = mt.y / Nn;
    e.z = mt.z / Nn;
    e.w = mt.w / Nn;
    *(float4*)(emb_out + i0) = e;
}

// ---------------------------------------------------------------------------
extern "C" void kernel_launch(void* const* d_in, const int* in_sizes, int n_in,
                              void* d_out, int out_size, void* d_ws, size_t ws_size,
                              hipStream_t stream) {
    const float* ze = (const float*)d_in[0];
    const float* W  = (const float*)d_in[1];
    const float* mt = (const float*)d_in[2];
    const float* Nt = (const float*)d_in[3];

    float* out    = (float*)d_out;
    float* zq_out = out + OFF_ZQ;
    float* commit = out + OFF_COMMIT;
    float* idxf   = out + OFF_IDX;
    float* emb    = out + OFF_EMB;
    float* mtn    = out + OFF_MT;
    float* ntn    = out + OFF_NT;

    // ---- scratch map (all consumed before the real outputs are written) ----
    // zq region:  zh (NN*DD halfs, 1st half) | wh (KN*DD halfs) | wsq (KN f)
    //             -> all consumed by screen; select then overwrites with zq.
    // emb+mt:     tmin2 as u32 lo/hi split (exactly 4,194,304 u32 = both
    //             regions; emb base is 4B-aligned only, hence no u64).
    //             After select, the area is reused: partial slots (stride-4,
    //             written by select into its own consumed slots), then
    //             offsets/perm/codes/prec/pdata; mt pre-init at scatter.
    // nt region:  hist (KN u32) -> converted in place to nt_new by prefix.
    _Float16* zh = (_Float16*)zq_out;                       // 16.7 MB
    _Float16* wh = (_Float16*)(zq_out + (size_t)NN * DD / 2);   // 4 MB, 16B ok
    float* wsqbuf = zq_out + (size_t)NN * DD / 2 + (size_t)KN * DD / 2;
    unsigned* tlo = (unsigned*)emb;                         // 64*NN u32
    unsigned* thi = tlo + (size_t)64 * NN;                  // 64*NN u32
    float* partials = (float*)tlo;                          // slot b at [4b]
    unsigned* offsets = tlo;                                // [0, 8192)
    unsigned* perm    = tlo + 8192;                         // [8192, 40960)
    unsigned* codes   = tlo + 40960;                        // [40960, 73728)
    unsigned* prec    = tlo + 73728;                        // [73728, 75776)
    float*    pdata   = (float*)tlo + 75779;                // 16B-aligned, 2MB
    unsigned* hist    = (unsigned*)ntn;                     // KN u32
    float*    nws     = (float*)d_ws;                       // 1 float

    // 1) fused prep: ze->f16, W->f16 + ||w||^2, hist zero
    prep_kernel<<<(NN * DD / 4) / 256, 256, 0, stream>>>(
        ze, W, zh, wh, wsqbuf, hist);

    // 2) f16 screening GEMM -> per-(point,tile) top-2 records (lo/hi)
    screen_kernel<<<(NN / 128) * (KN / 128), 256, 0, stream>>>(
        zh, wh, wsqbuf, tlo, thi);

    // 3) fused select: window compaction (LDS) + exact rescore + zq +
    //    histogram + commit partial (into consumed tmin2 slot)
    select_kernel<<<NN / 4, 256, 0, stream>>>(
        tlo, thi, ze, W, idxf, zq_out, hist, partials);

    // 4) prefix over histogram -> offsets; nt_new; commit; n
    prefix_kernel<<<1, 256, 0, stream>>>(Nt, ntn, partials, commit,
                                         offsets, nws);

    // 5) counting-sort scatter -> perm + codes; fused mt pre-init = g*mt
    scatter_kernel<<<(KN * DD / 4) / 256, 256, 0, stream>>>(
        idxf, offsets, perm, codes, mt, mtn);

    // 6) segmented sum level 1: balanced chunks, direct interior writes
    mt1_kernel<<<NCH1 / 4, 256, 0, stream>>>(ze, mt, perm, codes, mtn,
                                             prec, pdata);

    // 7) segmented sum level 2: records, atomic only at chunk boundaries
    mt2_kernel<<<NCH2 / 4, 256, 0, stream>>>(mt, prec, pdata, mtn);

    // 8) emb = mt_new / Nn
    final_kernel<<<(KN * DD / 4) / 256, 256, 0, stream>>>(ntn, mtn, nws, emb);
}